// Round 15
// baseline (1835.574 us; speedup 1.0000x reference)
//
#include <hip/hip_runtime.h>
#include <hip/hip_fp16.h>
#include <hip/hip_fp8.h>
#include <math.h>

#define L 1024
#define BATCH 32
#define TS 64
#define PADF 65
#define PADU 66
#define NT 16
#define NPAIRS 136
#define STEPS 20

struct __align__(8) us4 { unsigned short x, y, z, w; };
struct __align__(4) uc4 { unsigned char x, y, z, w; };
typedef float vf4 __attribute__((ext_vector_type(4)));

__device__ __forceinline__ float4 ld4(const float* p){ return *(const float4*)p; }
__device__ __forceinline__ float4 ld4_nt(const float* p){
  vf4 v = __builtin_nontemporal_load((const vf4*)p);
  float4 r; r.x=v.x; r.y=v.y; r.z=v.z; r.w=v.w; return r;
}
__device__ __forceinline__ void st4_nt(float* p, float a, float b, float c, float d){
  vf4 v; v.x=a; v.y=b; v.z=c; v.w=d;
  __builtin_nontemporal_store(v, (vf4*)p);
}
__device__ __forceinline__ unsigned short f2h(float x){
  __half h = __float2half(x);
  return *(unsigned short*)&h;
}
__device__ __forceinline__ float h2f(unsigned short u){
  __half h; *(unsigned short*)&h = u;
  return __half2float(h);
}
__device__ __forceinline__ unsigned char f2q(float x){
  __hip_fp8_e4m3 q(x);
  return (unsigned char)q.__x;
}
__device__ __forceinline__ float q2f(unsigned char u){
  __hip_fp8_e4m3 q;
  q.__x = (__hip_fp8_storage_t)u;
  return (float)q;
}
__device__ __forceinline__ float red16(float v){
  v += __shfl_xor(v, 1); v += __shfl_xor(v, 2);
  v += __shfl_xor(v, 4); v += __shfl_xor(v, 8);
  return v;
}
__device__ __forceinline__ void pair_decode(int p, int& bi, int& bj){
  bi = 0;
  while (p >= NT - bi){ p -= NT - bi; ++bi; }
  bj = bi + p;
}

// pbuf: [0..19] a_t; [20..39] beltc_t (0 for t=0, belt*lrb^(t-1) else); [40] w
__global__ void params_kernel(float* pbuf, const float* w,
                              const float* alpha, const float* belt,
                              const float* lra, const float* lrb) {
  int t = threadIdx.x;
  if (t < STEPS) {
    pbuf[t]         = alpha[0] * powf(lra[0], (float)t);
    pbuf[STEPS + t] = (t == 0) ? 0.f : belt[0] * powf(lrb[0], (float)(t - 1));
  }
  if (t == 0) pbuf[2*STEPS] = w[0];
}

// prep (unchanged, proven): Sb=fp8(S_bar); Mb=fp16(M); Rh=fp16(rho) (b==0);
// Hh=fp16(scores); rowsum partials of A0 into rs0.
__global__ __launch_bounds__(256, 7)
void prep_kernel(const float* __restrict__ scores, const float* __restrict__ Mm,
                 const float* __restrict__ rho, const float* __restrict__ s,
                 unsigned char* __restrict__ Sb, unsigned short* __restrict__ Mb,
                 unsigned short* __restrict__ Rh, unsigned short* __restrict__ Hh,
                 float* __restrict__ rsOut)
{
  __shared__ float buf1[TS*PADF];
  __shared__ unsigned char buf2[TS*PADU];
  const int b = blockIdx.y;
  int bi, bj; pair_decode(blockIdx.x, bi, bj);
  const bool diag = (bi == bj);
  const int ibase = bi*TS, jbase = bj*TS;
  const int tid = threadIdx.x, cgi = tid & 15, rr = tid >> 4, c4 = cgi*4;
  const size_t bb = (size_t)b << 20;
  const float sv = s[0];

  #pragma unroll
  for (int it = 0; it < 4; ++it){
    int row = it*16 + rr;
    size_t off = bb + ((size_t)(jbase+row)<<10) + ibase + c4;
    float4 v = ld4_nt(scores + off);
    float* d = &buf1[row*PADF + c4];
    d[0]=v.x; d[1]=v.y; d[2]=v.z; d[3]=v.w;
    us4 ho = {f2h(v.x),f2h(v.y),f2h(v.z),f2h(v.w)};
    *(us4*)(Hh + off) = ho;
  }
  __syncthreads();

  #pragma unroll
  for (int it = 0; it < 4; ++it){
    int ii = it*16 + rr;
    size_t offr = ((size_t)(ibase+ii)<<10) + jbase + c4;
    size_t off = bb + offr;
    float4 s4 = ld4_nt(scores + off);
    float4 m4 = ld4_nt(Mm + off);
    if (b == 0){
      float4 r4 = ld4_nt(rho + offr);
      us4 ro = {f2h(r4.x),f2h(r4.y),f2h(r4.z),f2h(r4.w)};
      *(us4*)(Rh + offr) = ro;
    }
    float sc[4] = {s4.x,s4.y,s4.z,s4.w};
    float m [4] = {m4.x,m4.y,m4.z,m4.w};
    unsigned char qs[4];
    unsigned short qm[4], qh[4];
    float part = 0.f;
    #pragma unroll
    for (int k = 0; k < 4; ++k){
      float scT = buf1[(c4+k)*PADF + ii];
      float sbv = 0.5f*(sc[k] + scT) - sv;
      unsigned char q = f2q(sbv);
      buf2[ii*PADU + c4 + k] = q;
      part += (q2f(q) + sv) * m[k];
      qs[k]=q; qm[k]=f2h(m[k]); qh[k]=f2h(sc[k]);
    }
    uc4 so = {qs[0],qs[1],qs[2],qs[3]}; *(uc4*)(Sb + off) = so;
    us4 mo = {qm[0],qm[1],qm[2],qm[3]}; *(us4*)(Mb + off) = mo;
    us4 ho = {qh[0],qh[1],qh[2],qh[3]}; *(us4*)(Hh + off) = ho;
    part = red16(part);
    if (cgi == 0) rsOut[((size_t)(b*NT + bj)<<10) + ibase + ii] = part;
  }
  __syncthreads();

  if (!diag){
    #pragma unroll
    for (int it = 0; it < 4; ++it){
      int jj = it*16 + rr;
      size_t offr = ((size_t)(jbase+jj)<<10) + ibase + c4;
      size_t off = bb + offr;
      float4 m4 = ld4_nt(Mm + off);
      if (b == 0){
        float4 r4 = ld4_nt(rho + offr);
        us4 ro = {f2h(r4.x),f2h(r4.y),f2h(r4.z),f2h(r4.w)};
        *(us4*)(Rh + offr) = ro;
      }
      float m[4] = {m4.x,m4.y,m4.z,m4.w};
      unsigned char qs[4];
      unsigned short qm[4];
      float part = 0.f;
      #pragma unroll
      for (int k = 0; k < 4; ++k){
        unsigned char q = buf2[(c4+k)*PADU + jj];
        part += (q2f(q) + sv) * m[k];
        qs[k]=q; qm[k]=f2h(m[k]);
      }
      uc4 so = {qs[0],qs[1],qs[2],qs[3]}; *(uc4*)(Sb + off) = so;
      us4 mo = {qm[0],qm[1],qm[2],qm[3]}; *(us4*)(Mb + off) = mo;
      part = red16(part);
      if (cgi == 0) rsOut[((size_t)(b*NT + bi)<<10) + jbase + jj] = part;
    }
  }
}

// one step (round-13 structure + cross-barrier register prefetch).
// LAST writes f32 A to Aout. Numerics identical to round 13.
template<bool LAST>
__global__ __launch_bounds__(256, LAST ? 4 : 6)
void step_kernel(const unsigned char* __restrict__ Sb,
                 const unsigned short* __restrict__ Mb,
                 const unsigned short* __restrict__ Rh,
                 unsigned short* __restrict__ Hh,
                 const float* __restrict__ rsIn, float* __restrict__ rsOut,
                 const float* __restrict__ LmIn, float* __restrict__ LmOut,
                 const float* __restrict__ pbuf,
                 float* __restrict__ Aout, const int t)
{
  __shared__ unsigned short bufP[TS*PADU];   // Hn_ij fp16
  __shared__ unsigned short bufQ[TS*PADU];   // Hn_ji fp16
  __shared__ float cbuf[2*TS];

  const int b = blockIdx.y;
  int bi, bj; pair_decode(blockIdx.x, bi, bj);
  const bool diag = (bi == bj);
  const int ibase = bi*TS, jbase = bj*TS;
  const int tid = threadIdx.x, cgi = tid & 15, rr = tid >> 4, c4 = cgi*4;
  const size_t bb = (size_t)b << 20;
  const float a_t = pbuf[t];
  const float beltc = pbuf[STEPS + t];
  const float w_ = pbuf[2*STEPS];

  // ---- prefetch phase-A operands (issued before c-phase barrier) ----
  us4 huA[4], muA[4], ruA[4];
  uc4 suA[4];
  #pragma unroll
  for (int it = 0; it < 4; ++it){
    const int ii = it*16 + rr;
    const size_t offr = ((size_t)(ibase+ii)<<10) + jbase + c4;
    const size_t off = bb + offr;
    huA[it] = *(const us4*)(Hh + off);
    muA[it] = *(const us4*)(Mb + off);
    suA[it] = *(const uc4*)(Sb + off);
    ruA[it] = *(const us4*)(Rh + offr);
  }

  // ---- c phase (overlaps with prefetch in flight) ----
  if (tid < 128){
    const int half = tid >> 6, lane = tid & 63;
    const int rowbase = half ? jbase : ibase;
    const float* rp = rsIn + ((size_t)(b*NT)<<10) + rowbase + lane;
    float rs = 0.f;
    #pragma unroll
    for (int pq = 0; pq < NT; ++pq) rs += rp[(size_t)pq << 10];
    const float rowm = rs - 1.0f;
    const float rl = fmaxf(rowm, 0.f);
    const float lm = (t == 0) ? (w_ * rl)
                              : (LmIn[((size_t)b<<10) + rowbase + lane] + beltc * rl);
    const float sg = (rowm > 0.f) ? 1.f : ((rowm < 0.f) ? -1.f : 0.f);
    cbuf[tid] = lm * sg;
    if (!LAST && half == 0) LmOut[((size_t)b<<10) + rowbase + lane] = lm;
  }
  __syncthreads();

  float mR[4][4], part1[4];

  // ---- phase A: tile-ij update from prefetched regs ----
  #pragma unroll
  for (int it = 0; it < 4; ++it){
    const int ii = it*16 + rr;
    const size_t off = bb + ((size_t)(ibase+ii)<<10) + jbase + c4;
    float h [4] = {h2f(huA[it].x),h2f(huA[it].y),h2f(huA[it].z),h2f(huA[it].w)};
    float m [4] = {h2f(muA[it].x),h2f(muA[it].y),h2f(muA[it].z),h2f(muA[it].w)};
    float sb[4] = {q2f(suA[it].x),q2f(suA[it].y),q2f(suA[it].z),q2f(suA[it].w)};
    float rh[4] = {h2f(ruA[it].x),h2f(ruA[it].y),h2f(ruA[it].z),h2f(ruA[it].w)};
    const float ci = cbuf[ii];
    float p1 = 0.f;
    unsigned short bits[4];
    #pragma unroll
    for (int k = 0; k < 4; ++k){
      const float g = sb[k] - ci - cbuf[TS + c4 + k];
      float x = fmaf(a_t * h[k] * m[k], g, h[k]);
      x = fminf(fmaxf(fabsf(x) - rh[k]*a_t, 0.f), 1.f);
      bits[k] = f2h(x);
      bufP[ii*PADU + c4 + k] = bits[k];
      p1 += 0.5f * h2f(bits[k]) * m[k];
      mR[it][k] = m[k];
    }
    part1[it] = p1;
    if (!LAST){
      us4 ho = {bits[0],bits[1],bits[2],bits[3]};
      *(us4*)(Hh + off) = ho;
    }
  }

  // ---- prefetch phase-B operands (issued before phase-A barrier) ----
  us4 huB[4], muB[4], ruB[4];
  uc4 suB[4];
  if (!diag){
    #pragma unroll
    for (int it = 0; it < 4; ++it){
      const int jj = it*16 + rr;
      const size_t offr = ((size_t)(jbase+jj)<<10) + ibase + c4;
      const size_t off = bb + offr;
      huB[it] = *(const us4*)(Hh + off);
      muB[it] = *(const us4*)(Mb + off);
      suB[it] = *(const uc4*)(Sb + off);
      ruB[it] = *(const us4*)(Rh + offr);
    }
  }
  __syncthreads();

  // ---- phase B: tile-ji update from prefetched regs ----
  if (!diag){
    #pragma unroll
    for (int it = 0; it < 4; ++it){
      const int jj = it*16 + rr;
      const size_t off = bb + ((size_t)(jbase+jj)<<10) + ibase + c4;
      float h [4] = {h2f(huB[it].x),h2f(huB[it].y),h2f(huB[it].z),h2f(huB[it].w)};
      float m [4] = {h2f(muB[it].x),h2f(muB[it].y),h2f(muB[it].z),h2f(muB[it].w)};
      float sb[4] = {q2f(suB[it].x),q2f(suB[it].y),q2f(suB[it].z),q2f(suB[it].w)};
      float rh[4] = {h2f(ruB[it].x),h2f(ruB[it].y),h2f(ruB[it].z),h2f(ruB[it].w)};
      const float cjj = cbuf[TS + jj];
      float part = 0.f;
      float av[4];
      unsigned short bits[4];
      #pragma unroll
      for (int k = 0; k < 4; ++k){
        const float g = sb[k] - cjj - cbuf[c4 + k];
        float x = fmaf(a_t * h[k] * m[k], g, h[k]);
        x = fminf(fmaxf(fabsf(x) - rh[k]*a_t, 0.f), 1.f);
        bits[k] = f2h(x);
        bufQ[jj*PADU + c4 + k] = bits[k];
        const float hT = h2f(bufP[(c4+k)*PADU + jj]);
        if (LAST) av[k] = 0.5f*(x + hT)*m[k];
        else      part += 0.5f*(h2f(bits[k]) + hT)*m[k];
      }
      if (LAST){
        st4_nt(Aout + off, av[0], av[1], av[2], av[3]);
      } else {
        us4 ho = {bits[0],bits[1],bits[2],bits[3]};
        *(us4*)(Hh + off) = ho;
        part = red16(part);
        if (cgi == 0) rsOut[((size_t)(b*NT + bi)<<10) + jbase + jj] = part;
      }
    }
  }
  __syncthreads();

  // ---- phase C: rows-i partials (or final A_ij), M from registers ----
  const unsigned short* hs = diag ? bufP : bufQ;
  #pragma unroll
  for (int it = 0; it < 4; ++it){
    const int ii = it*16 + rr;
    if (LAST){
      float av[4];
      #pragma unroll
      for (int k = 0; k < 4; ++k){
        float hv = h2f(bufP[ii*PADU + c4 + k]);
        float hT = h2f(hs[(c4+k)*PADU + ii]);
        av[k] = 0.5f*(hv + hT)*mR[it][k];
      }
      const size_t off = bb + ((size_t)(ibase+ii)<<10) + jbase + c4;
      st4_nt(Aout + off, av[0], av[1], av[2], av[3]);
    } else {
      float part = part1[it];
      #pragma unroll
      for (int k = 0; k < 4; ++k)
        part += 0.5f * h2f(hs[(c4+k)*PADU + ii]) * mR[it][k];
      part = red16(part);
      if (cgi == 0) rsOut[((size_t)(b*NT + bj)<<10) + ibase + ii] = part;
    }
  }
}

extern "C" void kernel_launch(void* const* d_in, const int* in_sizes, int n_in,
                              void* d_out, int out_size, void* d_ws, size_t ws_size,
                              hipStream_t stream) {
  const float* scores = (const float*)d_in[0];
  const float* Mm     = (const float*)d_in[1];
  const float* rho    = (const float*)d_in[2];
  const float* s      = (const float*)d_in[3];
  const float* w      = (const float*)d_in[4];
  const float* alpha  = (const float*)d_in[5];
  const float* belt   = (const float*)d_in[6];
  const float* lra    = (const float*)d_in[7];
  const float* lrb    = (const float*)d_in[8];
  float* Aout = (float*)d_out;

  const size_t SBB = (size_t)BATCH*L*L*1;   // fp8 S_bar, 33.5MB
  const size_t MBB = (size_t)BATCH*L*L*2;   // fp16 M, 67MB
  const size_t HHB = (size_t)BATCH*L*L*2;   // fp16 H, 67MB
  const size_t RHB = (size_t)L*L*2;         // fp16 rho, 2MB
  const size_t RSB = (size_t)BATCH*NT*L*4;  // 2MB
  const size_t LMB = (size_t)BATCH*L*4;     // 128KB

  char* wp = (char*)d_ws;
  size_t off = 0;
  unsigned char*  Sb = (unsigned char*)(wp + off);  off += SBB;
  unsigned short* Mb = (unsigned short*)(wp + off); off += MBB;
  unsigned short* Hh = (unsigned short*)(wp + off); off += HHB;
  unsigned short* Rh = (unsigned short*)(wp + off); off += RHB;
  float* rs0 = (float*)(wp + off); off += RSB;
  float* rs1 = (float*)(wp + off); off += RSB;
  float* lm0 = (float*)(wp + off); off += LMB;
  float* lm1 = (float*)(wp + off); off += LMB;
  float* pbuf = (float*)(wp + off); off += 256;
  if (off > ws_size) return;

  params_kernel<<<1, 64, 0, stream>>>(pbuf, w, alpha, belt, lra, lrb);

  dim3 g2(NPAIRS, BATCH);
  prep_kernel<<<g2, 256, 0, stream>>>(scores, Mm, rho, s, Sb, Mb, Rh, Hh, rs0);
  for (int t = 0; t < STEPS; ++t){
    const float* rsIn = (t & 1) ? rs1 : rs0;
    float* rsOut      = (t & 1) ? rs0 : rs1;
    const float* LmIn = (t & 1) ? lm0 : lm1;
    float* LmOut      = (t & 1) ? lm1 : lm0;
    if (t == STEPS-1)
      step_kernel<true ><<<g2, 256, 0, stream>>>(Sb, Mb, Rh, Hh, rsIn, rsOut, LmIn, LmOut,
                                                 pbuf, Aout, t);
    else
      step_kernel<false><<<g2, 256, 0, stream>>>(Sb, Mb, Rh, Hh, rsIn, rsOut, LmIn, LmOut,
                                                 pbuf, Aout, t);
  }
}

// Round 16
// 1359.559 us; speedup vs baseline: 1.3501x; 1.3501x over previous
//
#include <hip/hip_runtime.h>
#include <hip/hip_fp16.h>
#include <hip/hip_fp8.h>
#include <math.h>

#define L 1024
#define BATCH 32
#define TS 64
#define PADF 65
#define PADU 66
#define NT 16
#define NPAIRS 136
#define STEPS 20

struct __align__(8) us4 { unsigned short x, y, z, w; };
struct __align__(4) uc4 { unsigned char x, y, z, w; };
typedef float vf4 __attribute__((ext_vector_type(4)));

__device__ __forceinline__ float4 ld4(const float* p){ return *(const float4*)p; }
__device__ __forceinline__ float4 ld4_nt(const float* p){
  vf4 v = __builtin_nontemporal_load((const vf4*)p);
  float4 r; r.x=v.x; r.y=v.y; r.z=v.z; r.w=v.w; return r;
}
__device__ __forceinline__ void st4_nt(float* p, float a, float b, float c, float d){
  vf4 v; v.x=a; v.y=b; v.z=c; v.w=d;
  __builtin_nontemporal_store(v, (vf4*)p);
}
__device__ __forceinline__ unsigned short f2h(float x){
  __half h = __float2half(x);
  return *(unsigned short*)&h;
}
__device__ __forceinline__ float h2f(unsigned short u){
  __half h; *(unsigned short*)&h = u;
  return __half2float(h);
}
__device__ __forceinline__ unsigned char f2q(float x){
  __hip_fp8_e4m3 q(x);
  return (unsigned char)q.__x;
}
__device__ __forceinline__ float q2f(unsigned char u){
  __hip_fp8_e4m3 q;
  q.__x = (__hip_fp8_storage_t)u;
  return (float)q;
}
__device__ __forceinline__ float red16(float v){
  v += __shfl_xor(v, 1); v += __shfl_xor(v, 2);
  v += __shfl_xor(v, 4); v += __shfl_xor(v, 8);
  return v;
}
__device__ __forceinline__ void pair_decode(int p, int& bi, int& bj){
  bi = 0;
  while (p >= NT - bi){ p -= NT - bi; ++bi; }
  bj = bi + p;
}

// pbuf: [0..19] a_t; [20..39] beltc_t (0 for t=0, belt*lrb^(t-1) else); [40] w
__global__ void params_kernel(float* pbuf, const float* w,
                              const float* alpha, const float* belt,
                              const float* lra, const float* lrb) {
  int t = threadIdx.x;
  if (t < STEPS) {
    pbuf[t]         = alpha[0] * powf(lra[0], (float)t);
    pbuf[STEPS + t] = (t == 0) ? 0.f : belt[0] * powf(lrb[0], (float)(t - 1));
  }
  if (t == 0) pbuf[2*STEPS] = w[0];
}

// rs layout: [b][row][tile] -> index ((b*L + row) << 4) + tile  (contiguous 16/row)

// prep: Sb=fp8(S_bar); Mb=fp16(M); Rh=fp16(rho) (b==0); Hh=fp16(scores);
// rowsum partials of A0 into rs0 (transposed layout).
__global__ __launch_bounds__(256, 7)
void prep_kernel(const float* __restrict__ scores, const float* __restrict__ Mm,
                 const float* __restrict__ rho, const float* __restrict__ s,
                 unsigned char* __restrict__ Sb, unsigned short* __restrict__ Mb,
                 unsigned short* __restrict__ Rh, unsigned short* __restrict__ Hh,
                 float* __restrict__ rsOut)
{
  __shared__ float buf1[TS*PADF];
  __shared__ unsigned char buf2[TS*PADU];
  const int b = blockIdx.y;
  int bi, bj; pair_decode(blockIdx.x, bi, bj);
  const bool diag = (bi == bj);
  const int ibase = bi*TS, jbase = bj*TS;
  const int tid = threadIdx.x, cgi = tid & 15, rr = tid >> 4, c4 = cgi*4;
  const size_t bb = (size_t)b << 20;
  const float sv = s[0];

  #pragma unroll
  for (int it = 0; it < 4; ++it){
    int row = it*16 + rr;
    size_t off = bb + ((size_t)(jbase+row)<<10) + ibase + c4;
    float4 v = ld4_nt(scores + off);
    float* d = &buf1[row*PADF + c4];
    d[0]=v.x; d[1]=v.y; d[2]=v.z; d[3]=v.w;
    us4 ho = {f2h(v.x),f2h(v.y),f2h(v.z),f2h(v.w)};
    *(us4*)(Hh + off) = ho;
  }
  __syncthreads();

  #pragma unroll
  for (int it = 0; it < 4; ++it){
    int ii = it*16 + rr;
    size_t offr = ((size_t)(ibase+ii)<<10) + jbase + c4;
    size_t off = bb + offr;
    float4 s4 = ld4_nt(scores + off);
    float4 m4 = ld4_nt(Mm + off);
    if (b == 0){
      float4 r4 = ld4_nt(rho + offr);
      us4 ro = {f2h(r4.x),f2h(r4.y),f2h(r4.z),f2h(r4.w)};
      *(us4*)(Rh + offr) = ro;
    }
    float sc[4] = {s4.x,s4.y,s4.z,s4.w};
    float m [4] = {m4.x,m4.y,m4.z,m4.w};
    unsigned char qs[4];
    unsigned short qm[4], qh[4];
    float part = 0.f;
    #pragma unroll
    for (int k = 0; k < 4; ++k){
      float scT = buf1[(c4+k)*PADF + ii];
      float sbv = 0.5f*(sc[k] + scT) - sv;
      unsigned char q = f2q(sbv);
      buf2[ii*PADU + c4 + k] = q;
      part += (q2f(q) + sv) * m[k];
      qs[k]=q; qm[k]=f2h(m[k]); qh[k]=f2h(sc[k]);
    }
    uc4 so = {qs[0],qs[1],qs[2],qs[3]}; *(uc4*)(Sb + off) = so;
    us4 mo = {qm[0],qm[1],qm[2],qm[3]}; *(us4*)(Mb + off) = mo;
    us4 ho = {qh[0],qh[1],qh[2],qh[3]}; *(us4*)(Hh + off) = ho;
    part = red16(part);
    if (cgi == 0) rsOut[(((size_t)(b<<10) + ibase + ii) << 4) + bj] = part;
  }
  __syncthreads();

  if (!diag){
    #pragma unroll
    for (int it = 0; it < 4; ++it){
      int jj = it*16 + rr;
      size_t offr = ((size_t)(jbase+jj)<<10) + ibase + c4;
      size_t off = bb + offr;
      float4 m4 = ld4_nt(Mm + off);
      if (b == 0){
        float4 r4 = ld4_nt(rho + offr);
        us4 ro = {f2h(r4.x),f2h(r4.y),f2h(r4.z),f2h(r4.w)};
        *(us4*)(Rh + offr) = ro;
      }
      float m[4] = {m4.x,m4.y,m4.z,m4.w};
      unsigned char qs[4];
      unsigned short qm[4];
      float part = 0.f;
      #pragma unroll
      for (int k = 0; k < 4; ++k){
        unsigned char q = buf2[(c4+k)*PADU + jj];
        part += (q2f(q) + sv) * m[k];
        qs[k]=q; qm[k]=f2h(m[k]);
      }
      uc4 so = {qs[0],qs[1],qs[2],qs[3]}; *(uc4*)(Sb + off) = so;
      us4 mo = {qm[0],qm[1],qm[2],qm[3]}; *(us4*)(Mb + off) = mo;
      part = red16(part);
      if (cgi == 0) rsOut[(((size_t)(b<<10) + jbase + jj) << 4) + bi] = part;
    }
  }
}

// one step (round-13 structure, transposed rs). LAST writes f32 A to Aout.
template<bool LAST>
__global__ __launch_bounds__(256, LAST ? 4 : 7)
void step_kernel(const unsigned char* __restrict__ Sb,
                 const unsigned short* __restrict__ Mb,
                 const unsigned short* __restrict__ Rh,
                 unsigned short* __restrict__ Hh,
                 const float* __restrict__ rsIn, float* __restrict__ rsOut,
                 const float* __restrict__ LmIn, float* __restrict__ LmOut,
                 const float* __restrict__ pbuf,
                 float* __restrict__ Aout, const int t)
{
  __shared__ unsigned short bufP[TS*PADU];   // Hn_ij fp16
  __shared__ unsigned short bufQ[TS*PADU];   // Hn_ji fp16
  __shared__ float cbuf[2*TS];

  const int b = blockIdx.y;
  int bi, bj; pair_decode(blockIdx.x, bi, bj);
  const bool diag = (bi == bj);
  const int ibase = bi*TS, jbase = bj*TS;
  const int tid = threadIdx.x, cgi = tid & 15, rr = tid >> 4, c4 = cgi*4;
  const size_t bb = (size_t)b << 20;
  const float a_t = pbuf[t];
  const float beltc = pbuf[STEPS + t];
  const float w_ = pbuf[2*STEPS];

  // ---- c phase (contiguous 64B/thread reads) ----
  if (tid < 128){
    const int half = tid >> 6, lane = tid & 63;
    const int rowbase = half ? jbase : ibase;
    const float* rp = rsIn + (((size_t)(b<<10) + rowbase + lane) << 4);
    float rs = 0.f;
    #pragma unroll
    for (int pq = 0; pq < 4; ++pq){
      float4 v = ld4(rp + pq*4);
      rs += v.x; rs += v.y; rs += v.z; rs += v.w;
    }
    const float rowm = rs - 1.0f;
    const float rl = fmaxf(rowm, 0.f);
    const float lm = (t == 0) ? (w_ * rl)
                              : (LmIn[((size_t)b<<10) + rowbase + lane] + beltc * rl);
    const float sg = (rowm > 0.f) ? 1.f : ((rowm < 0.f) ? -1.f : 0.f);
    cbuf[tid] = lm * sg;
    if (!LAST && half == 0) LmOut[((size_t)b<<10) + rowbase + lane] = lm;
  }
  __syncthreads();

  float mR[4][4], part1[4];

  // ---- phase A: tile-ij update ----
  #pragma unroll
  for (int it = 0; it < 4; ++it){
    const int ii = it*16 + rr;
    const size_t offr = ((size_t)(ibase+ii)<<10) + jbase + c4;
    const size_t off = bb + offr;
    us4 hu = *(const us4*)(Hh + off);
    us4 mu = *(const us4*)(Mb + off);
    uc4 su = *(const uc4*)(Sb + off);
    us4 ru = *(const us4*)(Rh + offr);
    float h [4] = {h2f(hu.x),h2f(hu.y),h2f(hu.z),h2f(hu.w)};
    float m [4] = {h2f(mu.x),h2f(mu.y),h2f(mu.z),h2f(mu.w)};
    float sb[4] = {q2f(su.x),q2f(su.y),q2f(su.z),q2f(su.w)};
    float rh[4] = {h2f(ru.x),h2f(ru.y),h2f(ru.z),h2f(ru.w)};
    const float ci = cbuf[ii];
    float p1 = 0.f;
    unsigned short bits[4];
    #pragma unroll
    for (int k = 0; k < 4; ++k){
      const float g = sb[k] - ci - cbuf[TS + c4 + k];
      float x = fmaf(a_t * h[k] * m[k], g, h[k]);
      x = fminf(fmaxf(fabsf(x) - rh[k]*a_t, 0.f), 1.f);
      bits[k] = f2h(x);
      bufP[ii*PADU + c4 + k] = bits[k];
      p1 += 0.5f * h2f(bits[k]) * m[k];
      mR[it][k] = m[k];
    }
    part1[it] = p1;
    if (!LAST){
      us4 ho = {bits[0],bits[1],bits[2],bits[3]};
      *(us4*)(Hh + off) = ho;
    }
  }
  __syncthreads();

  // ---- phase B: tile-ji update ----
  if (!diag){
    #pragma unroll
    for (int it = 0; it < 4; ++it){
      const int jj = it*16 + rr;
      const size_t offr = ((size_t)(jbase+jj)<<10) + ibase + c4;
      const size_t off = bb + offr;
      us4 hu = *(const us4*)(Hh + off);
      us4 mu = *(const us4*)(Mb + off);
      uc4 su = *(const uc4*)(Sb + off);
      us4 ru = *(const us4*)(Rh + offr);
      float h [4] = {h2f(hu.x),h2f(hu.y),h2f(hu.z),h2f(hu.w)};
      float m [4] = {h2f(mu.x),h2f(mu.y),h2f(mu.z),h2f(mu.w)};
      float sb[4] = {q2f(su.x),q2f(su.y),q2f(su.z),q2f(su.w)};
      float rh[4] = {h2f(ru.x),h2f(ru.y),h2f(ru.z),h2f(ru.w)};
      const float cjj = cbuf[TS + jj];
      float part = 0.f;
      float av[4];
      unsigned short bits[4];
      #pragma unroll
      for (int k = 0; k < 4; ++k){
        const float g = sb[k] - cjj - cbuf[c4 + k];
        float x = fmaf(a_t * h[k] * m[k], g, h[k]);
        x = fminf(fmaxf(fabsf(x) - rh[k]*a_t, 0.f), 1.f);
        bits[k] = f2h(x);
        bufQ[jj*PADU + c4 + k] = bits[k];
        const float hT = h2f(bufP[(c4+k)*PADU + jj]);
        if (LAST) av[k] = 0.5f*(x + hT)*m[k];
        else      part += 0.5f*(h2f(bits[k]) + hT)*m[k];
      }
      if (LAST){
        st4_nt(Aout + off, av[0], av[1], av[2], av[3]);
      } else {
        us4 ho = {bits[0],bits[1],bits[2],bits[3]};
        *(us4*)(Hh + off) = ho;
        part = red16(part);
        if (cgi == 0) rsOut[(((size_t)(b<<10) + jbase + jj) << 4) + bi] = part;
      }
    }
  }
  __syncthreads();

  // ---- phase C: rows-i partials (or final A_ij), M from registers ----
  const unsigned short* hs = diag ? bufP : bufQ;
  #pragma unroll
  for (int it = 0; it < 4; ++it){
    const int ii = it*16 + rr;
    if (LAST){
      float av[4];
      #pragma unroll
      for (int k = 0; k < 4; ++k){
        float hv = h2f(bufP[ii*PADU + c4 + k]);
        float hT = h2f(hs[(c4+k)*PADU + ii]);
        av[k] = 0.5f*(hv + hT)*mR[it][k];
      }
      const size_t off = bb + ((size_t)(ibase+ii)<<10) + jbase + c4;
      st4_nt(Aout + off, av[0], av[1], av[2], av[3]);
    } else {
      float part = part1[it];
      #pragma unroll
      for (int k = 0; k < 4; ++k)
        part += 0.5f * h2f(hs[(c4+k)*PADU + ii]) * mR[it][k];
      part = red16(part);
      if (cgi == 0) rsOut[(((size_t)(b<<10) + ibase + ii) << 4) + bj] = part;
    }
  }
}

extern "C" void kernel_launch(void* const* d_in, const int* in_sizes, int n_in,
                              void* d_out, int out_size, void* d_ws, size_t ws_size,
                              hipStream_t stream) {
  const float* scores = (const float*)d_in[0];
  const float* Mm     = (const float*)d_in[1];
  const float* rho    = (const float*)d_in[2];
  const float* s      = (const float*)d_in[3];
  const float* w      = (const float*)d_in[4];
  const float* alpha  = (const float*)d_in[5];
  const float* belt   = (const float*)d_in[6];
  const float* lra    = (const float*)d_in[7];
  const float* lrb    = (const float*)d_in[8];
  float* Aout = (float*)d_out;

  const size_t SBB = (size_t)BATCH*L*L*1;   // fp8 S_bar, 33.5MB
  const size_t MBB = (size_t)BATCH*L*L*2;   // fp16 M, 67MB
  const size_t HHB = (size_t)BATCH*L*L*2;   // fp16 H, 67MB
  const size_t RHB = (size_t)L*L*2;         // fp16 rho, 2MB
  const size_t RSB = (size_t)BATCH*NT*L*4;  // 2MB
  const size_t LMB = (size_t)BATCH*L*4;     // 128KB

  char* wp = (char*)d_ws;
  size_t off = 0;
  unsigned char*  Sb = (unsigned char*)(wp + off);  off += SBB;
  unsigned short* Mb = (unsigned short*)(wp + off); off += MBB;
  unsigned short* Hh = (unsigned short*)(wp + off); off += HHB;
  unsigned short* Rh = (unsigned short*)(wp + off); off += RHB;
  float* rs0 = (float*)(wp + off); off += RSB;
  float* rs1 = (float*)(wp + off); off += RSB;
  float* lm0 = (float*)(wp + off); off += LMB;
  float* lm1 = (float*)(wp + off); off += LMB;
  float* pbuf = (float*)(wp + off); off += 256;
  if (off > ws_size) return;

  params_kernel<<<1, 64, 0, stream>>>(pbuf, w, alpha, belt, lra, lrb);

  dim3 g2(NPAIRS, BATCH);
  prep_kernel<<<g2, 256, 0, stream>>>(scores, Mm, rho, s, Sb, Mb, Rh, Hh, rs0);
  for (int t = 0; t < STEPS; ++t){
    const float* rsIn = (t & 1) ? rs1 : rs0;
    float* rsOut      = (t & 1) ? rs0 : rs1;
    const float* LmIn = (t & 1) ? lm0 : lm1;
    float* LmOut      = (t & 1) ? lm1 : lm0;
    if (t == STEPS-1)
      step_kernel<true ><<<g2, 256, 0, stream>>>(Sb, Mb, Rh, Hh, rsIn, rsOut, LmIn, LmOut,
                                                 pbuf, Aout, t);
    else
      step_kernel<false><<<g2, 256, 0, stream>>>(Sb, Mb, Rh, Hh, rsIn, rsOut, LmIn, LmOut,
                                                 pbuf, Aout, t);
  }
}

// Round 17
// 1147.345 us; speedup vs baseline: 1.5998x; 1.1850x over previous
//
#include <hip/hip_runtime.h>
#include <hip/hip_fp16.h>
#include <hip/hip_fp8.h>
#include <math.h>

#define L 1024
#define BATCH 32
#define TS 64
#define PADF 65
#define PADU 66
#define PSW 17     // packed u32 words per row of S LDS tile (16 + pad)
#define NT 16
#define NPAIRS 136
#define STEPS 20

struct __align__(8) us4 { unsigned short x, y, z, w; };
struct __align__(4) uc4 { unsigned char x, y, z, w; };
typedef float vf4 __attribute__((ext_vector_type(4)));

__device__ __forceinline__ float4 ld4(const float* p){ return *(const float4*)p; }
__device__ __forceinline__ float4 ld4_nt(const float* p){
  vf4 v = __builtin_nontemporal_load((const vf4*)p);
  float4 r; r.x=v.x; r.y=v.y; r.z=v.z; r.w=v.w; return r;
}
__device__ __forceinline__ void st4_nt(float* p, float a, float b, float c, float d){
  vf4 v; v.x=a; v.y=b; v.z=c; v.w=d;
  __builtin_nontemporal_store(v, (vf4*)p);
}
__device__ __forceinline__ unsigned short f2h(float x){
  __half h = __float2half(x);
  return *(unsigned short*)&h;
}
__device__ __forceinline__ float h2f(unsigned short u){
  __half h; *(unsigned short*)&h = u;
  return __half2float(h);
}
__device__ __forceinline__ unsigned char f2q(float x){
  __hip_fp8_e4m3 q(x);
  return (unsigned char)q.__x;
}
__device__ __forceinline__ float q2f(unsigned char u){
  __hip_fp8_e4m3 q;
  q.__x = (__hip_fp8_storage_t)u;
  return (float)q;
}
__device__ __forceinline__ float red16(float v){
  v += __shfl_xor(v, 1); v += __shfl_xor(v, 2);
  v += __shfl_xor(v, 4); v += __shfl_xor(v, 8);
  return v;
}
// LPT ordering: p in [0,120) -> off-diagonal (bi<bj, heavy, dispatched first);
// p in [120,136) -> diagonal (light, fills the tail).
__device__ __forceinline__ void pair_decode(int p, int& bi, int& bj){
  if (p >= 120){ bi = bj = p - 120; return; }
  bi = 0;
  while (p >= 15 - bi){ p -= 15 - bi; ++bi; }
  bj = bi + 1 + p;
}

// pbuf: [0..19] a_t; [20..39] beltc_t (0 for t=0, belt*lrb^(t-1) else); [40] w
__global__ void params_kernel(float* pbuf, const float* w,
                              const float* alpha, const float* belt,
                              const float* lra, const float* lrb) {
  int t = threadIdx.x;
  if (t < STEPS) {
    pbuf[t]         = alpha[0] * powf(lra[0], (float)t);
    pbuf[STEPS + t] = (t == 0) ? 0.f : belt[0] * powf(lrb[0], (float)(t - 1));
  }
  if (t == 0) pbuf[2*STEPS] = w[0];
}

// prep (round-13 semantics): Sb=fp8(S_bar); Mb=fp16(M); Rh=fp16(rho) (b==0);
// Hh=fp16(scores); rowsum partials of A0 into rs0 ([b][tile][row] layout).
__global__ __launch_bounds__(256, 7)
void prep_kernel(const float* __restrict__ scores, const float* __restrict__ Mm,
                 const float* __restrict__ rho, const float* __restrict__ s,
                 unsigned char* __restrict__ Sb, unsigned short* __restrict__ Mb,
                 unsigned short* __restrict__ Rh, unsigned short* __restrict__ Hh,
                 float* __restrict__ rsOut)
{
  __shared__ float buf1[TS*PADF];
  __shared__ unsigned char buf2[TS*PADU];
  const int b = blockIdx.y;
  int bi, bj; pair_decode(blockIdx.x, bi, bj);
  const bool diag = (bi == bj);
  const int ibase = bi*TS, jbase = bj*TS;
  const int tid = threadIdx.x, cgi = tid & 15, rr = tid >> 4, c4 = cgi*4;
  const size_t bb = (size_t)b << 20;
  const float sv = s[0];

  #pragma unroll
  for (int it = 0; it < 4; ++it){
    int row = it*16 + rr;
    size_t off = bb + ((size_t)(jbase+row)<<10) + ibase + c4;
    float4 v = ld4_nt(scores + off);
    float* d = &buf1[row*PADF + c4];
    d[0]=v.x; d[1]=v.y; d[2]=v.z; d[3]=v.w;
    us4 ho = {f2h(v.x),f2h(v.y),f2h(v.z),f2h(v.w)};
    *(us4*)(Hh + off) = ho;
  }
  __syncthreads();

  #pragma unroll
  for (int it = 0; it < 4; ++it){
    int ii = it*16 + rr;
    size_t offr = ((size_t)(ibase+ii)<<10) + jbase + c4;
    size_t off = bb + offr;
    float4 s4 = ld4_nt(scores + off);
    float4 m4 = ld4_nt(Mm + off);
    if (b == 0){
      float4 r4 = ld4_nt(rho + offr);
      us4 ro = {f2h(r4.x),f2h(r4.y),f2h(r4.z),f2h(r4.w)};
      *(us4*)(Rh + offr) = ro;
    }
    float sc[4] = {s4.x,s4.y,s4.z,s4.w};
    float m [4] = {m4.x,m4.y,m4.z,m4.w};
    unsigned char qs[4];
    unsigned short qm[4], qh[4];
    float part = 0.f;
    #pragma unroll
    for (int k = 0; k < 4; ++k){
      float scT = buf1[(c4+k)*PADF + ii];
      float sbv = 0.5f*(sc[k] + scT) - sv;
      unsigned char q = f2q(sbv);
      buf2[ii*PADU + c4 + k] = q;
      part += (q2f(q) + sv) * m[k];
      qs[k]=q; qm[k]=f2h(m[k]); qh[k]=f2h(sc[k]);
    }
    uc4 so = {qs[0],qs[1],qs[2],qs[3]}; *(uc4*)(Sb + off) = so;
    us4 mo = {qm[0],qm[1],qm[2],qm[3]}; *(us4*)(Mb + off) = mo;
    us4 ho = {qh[0],qh[1],qh[2],qh[3]}; *(us4*)(Hh + off) = ho;
    part = red16(part);
    if (cgi == 0) rsOut[((size_t)(b*NT + bj)<<10) + ibase + ii] = part;
  }
  __syncthreads();

  if (!diag){
    #pragma unroll
    for (int it = 0; it < 4; ++it){
      int jj = it*16 + rr;
      size_t offr = ((size_t)(jbase+jj)<<10) + ibase + c4;
      size_t off = bb + offr;
      float4 m4 = ld4_nt(Mm + off);
      if (b == 0){
        float4 r4 = ld4_nt(rho + offr);
        us4 ro = {f2h(r4.x),f2h(r4.y),f2h(r4.z),f2h(r4.w)};
        *(us4*)(Rh + offr) = ro;
      }
      float m[4] = {m4.x,m4.y,m4.z,m4.w};
      unsigned char qs[4];
      unsigned short qm[4];
      float part = 0.f;
      #pragma unroll
      for (int k = 0; k < 4; ++k){
        unsigned char q = buf2[(c4+k)*PADU + jj];
        part += (q2f(q) + sv) * m[k];
        qs[k]=q; qm[k]=f2h(m[k]);
      }
      uc4 so = {qs[0],qs[1],qs[2],qs[3]}; *(uc4*)(Sb + off) = so;
      us4 mo = {qm[0],qm[1],qm[2],qm[3]}; *(us4*)(Mb + off) = mo;
      part = red16(part);
      if (cgi == 0) rsOut[((size_t)(b*NT + bi)<<10) + jbase + jj] = part;
    }
  }
}

// one step (round-13 structure + Sb-symmetry LDS reuse in phase B).
// LAST writes f32 A to Aout. Numerics bit-identical to round 13.
template<bool LAST>
__global__ __launch_bounds__(256, LAST ? 6 : 7)
void step_kernel(const unsigned char* __restrict__ Sb,
                 const unsigned short* __restrict__ Mb,
                 const unsigned short* __restrict__ Rh,
                 unsigned short* __restrict__ Hh,
                 const float* __restrict__ rsIn, float* __restrict__ rsOut,
                 const float* __restrict__ LmIn, float* __restrict__ LmOut,
                 const float* __restrict__ pbuf,
                 float* __restrict__ Aout, const int t)
{
  __shared__ unsigned short bufP[TS*PADU];   // Hn_ij fp16
  __shared__ unsigned short bufQ[TS*PADU];   // Hn_ji fp16
  __shared__ unsigned int  bufS[TS*PSW];     // Sb_ij raw fp8 words (for phase B)
  __shared__ float cbuf[2*TS];

  const int b = blockIdx.y;
  int bi, bj; pair_decode(blockIdx.x, bi, bj);
  const bool diag = (bi == bj);
  const int ibase = bi*TS, jbase = bj*TS;
  const int tid = threadIdx.x, cgi = tid & 15, rr = tid >> 4, c4 = cgi*4;
  const size_t bb = (size_t)b << 20;
  const float a_t = pbuf[t];
  const float beltc = pbuf[STEPS + t];
  const float w_ = pbuf[2*STEPS];

  // ---- c phase ----
  if (tid < 128){
    const int half = tid >> 6, lane = tid & 63;
    const int rowbase = half ? jbase : ibase;
    const float* rp = rsIn + ((size_t)(b*NT)<<10) + rowbase + lane;
    float rs = 0.f;
    #pragma unroll
    for (int pq = 0; pq < NT; ++pq) rs += rp[(size_t)pq << 10];
    const float rowm = rs - 1.0f;
    const float rl = fmaxf(rowm, 0.f);
    const float lm = (t == 0) ? (w_ * rl)
                              : (LmIn[((size_t)b<<10) + rowbase + lane] + beltc * rl);
    const float sg = (rowm > 0.f) ? 1.f : ((rowm < 0.f) ? -1.f : 0.f);
    cbuf[tid] = lm * sg;
    if (!LAST && half == 0) LmOut[((size_t)b<<10) + rowbase + lane] = lm;
  }
  __syncthreads();

  float mR[4][4], part1[4];

  // ---- phase A: tile-ij update ----
  #pragma unroll
  for (int it = 0; it < 4; ++it){
    const int ii = it*16 + rr;
    const size_t offr = ((size_t)(ibase+ii)<<10) + jbase + c4;
    const size_t off = bb + offr;
    us4 hu = *(const us4*)(Hh + off);
    us4 mu = *(const us4*)(Mb + off);
    uc4 su = *(const uc4*)(Sb + off);
    us4 ru = *(const us4*)(Rh + offr);
    bufS[ii*PSW + cgi] = *(const unsigned int*)&su;   // stash raw fp8 word
    float h [4] = {h2f(hu.x),h2f(hu.y),h2f(hu.z),h2f(hu.w)};
    float m [4] = {h2f(mu.x),h2f(mu.y),h2f(mu.z),h2f(mu.w)};
    float sb[4] = {q2f(su.x),q2f(su.y),q2f(su.z),q2f(su.w)};
    float rh[4] = {h2f(ru.x),h2f(ru.y),h2f(ru.z),h2f(ru.w)};
    const float ci = cbuf[ii];
    float p1 = 0.f;
    unsigned short bits[4];
    #pragma unroll
    for (int k = 0; k < 4; ++k){
      const float g = sb[k] - ci - cbuf[TS + c4 + k];
      float x = fmaf(a_t * h[k] * m[k], g, h[k]);
      x = fminf(fmaxf(fabsf(x) - rh[k]*a_t, 0.f), 1.f);
      bits[k] = f2h(x);
      bufP[ii*PADU + c4 + k] = bits[k];
      p1 += 0.5f * h2f(bits[k]) * m[k];
      mR[it][k] = m[k];
    }
    part1[it] = p1;
    if (!LAST){
      us4 ho = {bits[0],bits[1],bits[2],bits[3]};
      *(us4*)(Hh + off) = ho;
    }
  }
  __syncthreads();

  // ---- phase B: tile-ji update (Sb from LDS via symmetry) ----
  if (!diag){
    #pragma unroll
    for (int it = 0; it < 4; ++it){
      const int jj = it*16 + rr;
      const size_t offr = ((size_t)(jbase+jj)<<10) + ibase + c4;
      const size_t off = bb + offr;
      us4 hu = *(const us4*)(Hh + off);
      us4 mu = *(const us4*)(Mb + off);
      us4 ru = *(const us4*)(Rh + offr);
      float h [4] = {h2f(hu.x),h2f(hu.y),h2f(hu.z),h2f(hu.w)};
      float m [4] = {h2f(mu.x),h2f(mu.y),h2f(mu.z),h2f(mu.w)};
      float rh[4] = {h2f(ru.x),h2f(ru.y),h2f(ru.z),h2f(ru.w)};
      // Sb_ji[jj][c4+k] = Sb_ij[c4+k][jj] : byte (jj&3) of word (c4+k)*PSW + (jj>>2)
      const int jw = jj >> 2, jb8 = (jj & 3) * 8;
      float sb[4];
      #pragma unroll
      for (int k = 0; k < 4; ++k)
        sb[k] = q2f((unsigned char)((bufS[(c4+k)*PSW + jw] >> jb8) & 0xffu));
      const float cjj = cbuf[TS + jj];
      float part = 0.f;
      float av[4];
      unsigned short bits[4];
      #pragma unroll
      for (int k = 0; k < 4; ++k){
        const float g = sb[k] - cjj - cbuf[c4 + k];
        float x = fmaf(a_t * h[k] * m[k], g, h[k]);
        x = fminf(fmaxf(fabsf(x) - rh[k]*a_t, 0.f), 1.f);
        bits[k] = f2h(x);
        bufQ[jj*PADU + c4 + k] = bits[k];
        const float hT = h2f(bufP[(c4+k)*PADU + jj]);
        if (LAST) av[k] = 0.5f*(x + hT)*m[k];
        else      part += 0.5f*(h2f(bits[k]) + hT)*m[k];
      }
      if (LAST){
        st4_nt(Aout + off, av[0], av[1], av[2], av[3]);
      } else {
        us4 ho = {bits[0],bits[1],bits[2],bits[3]};
        *(us4*)(Hh + off) = ho;
        part = red16(part);
        if (cgi == 0) rsOut[((size_t)(b*NT + bi)<<10) + jbase + jj] = part;
      }
    }
  }
  __syncthreads();

  // ---- phase C: rows-i partials (or final A_ij), M from registers ----
  const unsigned short* hs = diag ? bufP : bufQ;
  #pragma unroll
  for (int it = 0; it < 4; ++it){
    const int ii = it*16 + rr;
    if (LAST){
      float av[4];
      #pragma unroll
      for (int k = 0; k < 4; ++k){
        float hv = h2f(bufP[ii*PADU + c4 + k]);
        float hT = h2f(hs[(c4+k)*PADU + ii]);
        av[k] = 0.5f*(hv + hT)*mR[it][k];
      }
      const size_t off = bb + ((size_t)(ibase+ii)<<10) + jbase + c4;
      st4_nt(Aout + off, av[0], av[1], av[2], av[3]);
    } else {
      float part = part1[it];
      #pragma unroll
      for (int k = 0; k < 4; ++k)
        part += 0.5f * h2f(hs[(c4+k)*PADU + ii]) * mR[it][k];
      part = red16(part);
      if (cgi == 0) rsOut[((size_t)(b*NT + bj)<<10) + ibase + ii] = part;
    }
  }
}

extern "C" void kernel_launch(void* const* d_in, const int* in_sizes, int n_in,
                              void* d_out, int out_size, void* d_ws, size_t ws_size,
                              hipStream_t stream) {
  const float* scores = (const float*)d_in[0];
  const float* Mm     = (const float*)d_in[1];
  const float* rho    = (const float*)d_in[2];
  const float* s      = (const float*)d_in[3];
  const float* w      = (const float*)d_in[4];
  const float* alpha  = (const float*)d_in[5];
  const float* belt   = (const float*)d_in[6];
  const float* lra    = (const float*)d_in[7];
  const float* lrb    = (const float*)d_in[8];
  float* Aout = (float*)d_out;

  const size_t SBB = (size_t)BATCH*L*L*1;   // fp8 S_bar, 33.5MB
  const size_t MBB = (size_t)BATCH*L*L*2;   // fp16 M, 67MB
  const size_t HHB = (size_t)BATCH*L*L*2;   // fp16 H, 67MB
  const size_t RHB = (size_t)L*L*2;         // fp16 rho, 2MB
  const size_t RSB = (size_t)BATCH*NT*L*4;  // 2MB
  const size_t LMB = (size_t)BATCH*L*4;     // 128KB

  char* wp = (char*)d_ws;
  size_t off = 0;
  unsigned char*  Sb = (unsigned char*)(wp + off);  off += SBB;
  unsigned short* Mb = (unsigned short*)(wp + off); off += MBB;
  unsigned short* Hh = (unsigned short*)(wp + off); off += HHB;
  unsigned short* Rh = (unsigned short*)(wp + off); off += RHB;
  float* rs0 = (float*)(wp + off); off += RSB;
  float* rs1 = (float*)(wp + off); off += RSB;
  float* lm0 = (float*)(wp + off); off += LMB;
  float* lm1 = (float*)(wp + off); off += LMB;
  float* pbuf = (float*)(wp + off); off += 256;
  if (off > ws_size) return;

  params_kernel<<<1, 64, 0, stream>>>(pbuf, w, alpha, belt, lra, lrb);

  dim3 g2(NPAIRS, BATCH);
  prep_kernel<<<g2, 256, 0, stream>>>(scores, Mm, rho, s, Sb, Mb, Rh, Hh, rs0);
  for (int t = 0; t < STEPS; ++t){
    const float* rsIn = (t & 1) ? rs1 : rs0;
    float* rsOut      = (t & 1) ? rs0 : rs1;
    const float* LmIn = (t & 1) ? lm0 : lm1;
    float* LmOut      = (t & 1) ? lm1 : lm0;
    if (t == STEPS-1)
      step_kernel<true ><<<g2, 256, 0, stream>>>(Sb, Mb, Rh, Hh, rsIn, rsOut, LmIn, LmOut,
                                                 pbuf, Aout, t);
    else
      step_kernel<false><<<g2, 256, 0, stream>>>(Sb, Mb, Rh, Hh, rsIn, rsOut, LmIn, LmOut,
                                                 pbuf, Aout, t);
  }
}